// Round 10
// baseline (174.478 us; speedup 1.0000x reference)
//
#include <hip/hip_runtime.h>
#include <math.h>
#include <stdint.h>

namespace {

constexpr int Nseq = 1024;
constexpr int Dm = 768;
constexpr int threeD = 2304;
constexpr int Mrows = 8192;
constexpr int Hh = 12;
// scale (1/8) * log2(e)
constexpr float kScaleLog2 = 0.18033688011112042f;

using bf16x8 = __attribute__((ext_vector_type(8))) short;
using f32x4 = __attribute__((ext_vector_type(4))) float;
using f32x16 = __attribute__((ext_vector_type(16))) float;
using us4 = __attribute__((ext_vector_type(4))) unsigned short;

__device__ __forceinline__ unsigned short f2bf(float f) {
  union { float f; uint32_t u; } v;
  v.f = f;
  uint32_t r = v.u + 0x7fffu + ((v.u >> 16) & 1u);
  return (unsigned short)(r >> 16);
}

__device__ __forceinline__ float fexp2(float x) {
#if __has_builtin(__builtin_amdgcn_exp2f)
  return __builtin_amdgcn_exp2f(x);
#else
  float r;
  asm("v_exp_f32 %0, %1\n\ts_nop 0" : "=v"(r) : "v"(x));
  return r;
#endif
}

__device__ __forceinline__ uint32_t cvtpk_bf16(float lo, float hi) {
  uint32_t r;
  asm("v_cvt_pk_bf16_f32 %0, %1, %2" : "=v"(r) : "v"(lo), "v"(hi));
  return r;
}

__device__ __forceinline__ void gload_lds16(const void* g, void* l) {
  __builtin_amdgcn_global_load_lds(
      (const __attribute__((address_space(1))) unsigned int*)(uintptr_t)g,
      (__attribute__((address_space(3))) unsigned int*)(uintptr_t)l, 16, 0, 0);
}

// ---------------------------------------------------------------------------
// fp32 -> bf16 elementwise cast (vectorized 4/thread)
// ---------------------------------------------------------------------------
__global__ __launch_bounds__(256) void cast_f32_bf16(
    const float* __restrict__ in, unsigned short* __restrict__ outp, int n4) {
  int i = blockIdx.x * blockDim.x + threadIdx.x;
  if (i < n4) {
    float4 v = ((const float4*)in)[i];
    us4 u = {f2bf(v.x), f2bf(v.y), f2bf(v.z), f2bf(v.w)};
    ((us4*)outp)[i] = u;
  }
}

// ---------------------------------------------------------------------------
// W[K][N] fp32 -> Wt[N][K] bf16 (32x32 LDS tile transpose)
// ---------------------------------------------------------------------------
__global__ __launch_bounds__(256) void transpose_cast(
    const float* __restrict__ W, unsigned short* __restrict__ Wt, int K, int N) {
  __shared__ unsigned short tile[32][33];
  const int n0 = blockIdx.x * 32, k0 = blockIdx.y * 32;
  const int tx = threadIdx.x & 31, ty = threadIdx.x >> 5;
#pragma unroll
  for (int i = 0; i < 32; i += 8)
    tile[ty + i][tx] = f2bf(W[(size_t)(k0 + ty + i) * N + n0 + tx]);
  __syncthreads();
#pragma unroll
  for (int i = 0; i < 32; i += 8)
    Wt[(size_t)(n0 + ty + i) * K + k0 + tx] = tile[tx][ty + i];
}

// ---------------------------------------------------------------------------
// Phase-split MFMA GEMM: C = A[M][K] @ Bt[N][K]^T. Tile 128x256, BK=64,
// 8 waves (2M x 4N), 2 LDS K-tile buffers, per-K-tile 2 phases with
// interleaved staging; both-sides swizzle. (Unchanged from round 9.)
// MODE 0 (QKV, NCOLS=9): Q (pre-scaled) / K -> qkb, V -> vtb transposed.
// MODE 1 (proj, NCOLS=3): f32 out + bias.
// ---------------------------------------------------------------------------
template <int MODE, int NCOLS>
__global__ __launch_bounds__(512) void gemm8(
    const unsigned short* __restrict__ A, const unsigned short* __restrict__ Bt,
    void* __restrict__ C0, void* __restrict__ C1,
    const float* __restrict__ bias, int Kdim) {
  __shared__ unsigned short As[2][128 * 64];  // 32 KB
  __shared__ unsigned short Bs[2][256 * 64];  // 64 KB
  const int tid = threadIdx.x;  // 0..511
  const int wid = tid >> 6, lane = tid & 63;
  const int l15 = lane & 15, lg = lane >> 4;
  const int p = blockIdx.x;
  const int cpx = gridDim.x >> 3;
  const int l = (p & 7) * cpx + (p >> 3);
  const int row0 = (l / NCOLS) * 128, col0 = (l % NCOLS) * 256;
  const int wr = (wid >> 2) * 64, wc = (wid & 3) * 64;

  auto stageA = [&](int kt, int b, int r) {
    const int s = r * 512 + tid;
    const int row = s >> 3, c = s & 7;
    const int sc = c ^ (row & 7);
    gload_lds16(&A[(size_t)(row0 + row) * Kdim + kt * 64 + sc * 8],
                &As[b][(s & ~63) * 8]);
  };
  auto stageB = [&](int kt, int b, int r) {
    const int s = r * 512 + tid;
    const int row = s >> 3, c = s & 7;
    const int sc = c ^ (row & 7);
    gload_lds16(&Bt[(size_t)(col0 + row) * Kdim + kt * 64 + sc * 8],
                &Bs[b][(s & ~63) * 8]);
  };
  auto rdA = [&](int b, int m, int ks) {
    const int row = wr + m * 16 + l15;
    const int sc = (ks * 4 + lg) ^ (row & 7);
    return *(const bf16x8*)&As[b][(row * 8 + sc) * 8];
  };
  auto rdB = [&](int b, int n, int ks) {
    const int row = wc + n * 16 + l15;
    const int sc = (ks * 4 + lg) ^ (row & 7);
    return *(const bf16x8*)&Bs[b][(row * 8 + sc) * 8];
  };

  f32x4 acc[4][4] = {};
  stageA(0, 0, 0);
  stageA(0, 0, 1);
  stageB(0, 0, 0);
  stageB(0, 0, 1);
  stageB(0, 0, 2);
  stageB(0, 0, 3);
  asm volatile("s_waitcnt vmcnt(0)" ::: "memory");
  __builtin_amdgcn_s_barrier();

  const int NTK = Kdim / 64;  // 12
  for (int g = 0; g < NTK; ++g) {
    const int cur = g & 1;
    const int nb = cur ^ 1;
    const bool pf = (g + 1 < NTK);
    bf16x8 bfr[4][2], afr[2][2];
    // ---- phase 0: quadrant m=0..1 (all n) ----
#pragma unroll
    for (int n = 0; n < 4; ++n)
#pragma unroll
      for (int ks = 0; ks < 2; ++ks) bfr[n][ks] = rdB(cur, n, ks);
#pragma unroll
    for (int m = 0; m < 2; ++m)
#pragma unroll
      for (int ks = 0; ks < 2; ++ks) afr[m][ks] = rdA(cur, m, ks);
    if (pf) {
      stageA(g + 1, nb, 0);
      stageA(g + 1, nb, 1);
      stageB(g + 1, nb, 0);
    }
    __builtin_amdgcn_s_barrier();
    asm volatile("s_waitcnt lgkmcnt(0)" ::: "memory");
    __builtin_amdgcn_sched_barrier(0);
    __builtin_amdgcn_s_setprio(1);
#pragma unroll
    for (int m = 0; m < 2; ++m)
#pragma unroll
      for (int n = 0; n < 4; ++n)
#pragma unroll
        for (int ks = 0; ks < 2; ++ks)
          acc[m][n] = __builtin_amdgcn_mfma_f32_16x16x32_bf16(
              afr[m][ks], bfr[n][ks], acc[m][n], 0, 0, 0);
    __builtin_amdgcn_s_setprio(0);
    __builtin_amdgcn_s_barrier();
    // ---- phase 1: quadrant m=2..3 (all n) ----
#pragma unroll
    for (int m = 0; m < 2; ++m)
#pragma unroll
      for (int ks = 0; ks < 2; ++ks) afr[m][ks] = rdA(cur, m + 2, ks);
    if (pf) {
      stageB(g + 1, nb, 1);
      stageB(g + 1, nb, 2);
      stageB(g + 1, nb, 3);
    }
    __builtin_amdgcn_s_barrier();
    asm volatile("s_waitcnt lgkmcnt(0)" ::: "memory");
    __builtin_amdgcn_sched_barrier(0);
    __builtin_amdgcn_s_setprio(1);
#pragma unroll
    for (int m = 0; m < 2; ++m)
#pragma unroll
      for (int n = 0; n < 4; ++n)
#pragma unroll
        for (int ks = 0; ks < 2; ++ks)
          acc[m + 2][n] = __builtin_amdgcn_mfma_f32_16x16x32_bf16(
              afr[m][ks], bfr[n][ks], acc[m + 2][n], 0, 0, 0);
    __builtin_amdgcn_s_setprio(0);
    asm volatile("s_waitcnt vmcnt(0)" ::: "memory");
    __builtin_amdgcn_sched_barrier(0);
    __builtin_amdgcn_s_barrier();
  }

  if constexpr (MODE == 1) {
#pragma unroll
    for (int m = 0; m < 4; ++m)
#pragma unroll
      for (int n = 0; n < 4; ++n) {
        const int col = col0 + wc + n * 16 + l15;
#pragma unroll
        for (int rr = 0; rr < 4; ++rr)
          ((float*)C0)[(size_t)(row0 + wr + m * 16 + lg * 4 + rr) * Dm + col] =
              acc[m][n][rr] + bias[col];
      }
  } else {
    if (col0 < 1536) {  // Q/K -> qk buffer, stride 1536; Q pre-scaled
#pragma unroll
      for (int m = 0; m < 4; ++m)
#pragma unroll
        for (int n = 0; n < 4; ++n) {
          const int col = col0 + wc + n * 16 + l15;
          const float qs = (col < 768) ? kScaleLog2 : 1.f;
#pragma unroll
          for (int rr = 0; rr < 4; ++rr)
            ((unsigned short*)C0)[(size_t)(row0 + wr + m * 16 + lg * 4 + rr) *
                                      1536 + col] = f2bf(acc[m][n][rr] * qs);
        }
    } else {  // V -> vtb[(b*12+h)*64+d][1024], 4 consecutive tokens per store
#pragma unroll
      for (int m = 0; m < 4; ++m)
#pragma unroll
        for (int n = 0; n < 4; ++n) {
          const int c = col0 + wc + n * 16 + l15 - 1536;  // h*64+d
          const int row = row0 + wr + m * 16 + lg * 4;    // first of 4 tokens
          const int bb = row >> 10, n0 = row & 1023;
          us4 pk = {f2bf(acc[m][n][0]), f2bf(acc[m][n][1]), f2bf(acc[m][n][2]),
                    f2bf(acc[m][n][3])};
          *(us4*)&((unsigned short*)C1)[((size_t)bb * 768 + c) * 1024 + n0] = pk;
        }
    }
  }
}

// ---------------------------------------------------------------------------
// MFMA flash attention, LDS-FREE / BARRIER-FREE. With no-max exp2 softmax,
// row-sums are lane-local, so the 4 waves of a block need no communication.
// K/V per head = 256 KB, L2-resident per XCD (12 heads x 256 KB = 3 MB);
// fragment rows are re-read 4x within a wave, by 4 waves, and by 8 q-blocks
// -> L1 (32 KB: K+V tile = 16 KB) catches the re-reads. Each wave reads its
// MFMA fragments straight from global (bf16x8 = dwordx4 loads): V loads
// issue first (consumed ~400 cyc later in PV -> latency self-hides), K loads
// feed QK^T; waves are fully independent streams (max TLP, zero barriers).
// Block = 128 q-rows, 4 waves x 32 rows; XCD-chunked grid (768 = 8 x 96).
//   S^T[key][q] = mfma_32x32x16(Kfrag, Qfrag) -> lane owns q-row l31.
//   P = exp2(S) in-register; pack via v_cvt_pk_bf16_f32 + permlane32_swap.
//   O^T[d][q] = mfma(Vfrag, Pfrag) -> lane-local normalize at end.
// ---------------------------------------------------------------------------
__global__ __launch_bounds__(256) void attn_mfma(
    const unsigned short* __restrict__ qkb, const unsigned short* __restrict__ vtb,
    unsigned short* __restrict__ outb) {
  constexpr int NT = Nseq / 64;  // 16
  const int tid = threadIdx.x;
  const int wid = tid >> 6, lane = tid & 63;
  const int l31 = lane & 31, hi = lane >> 5;
  // XCD-chunked swizzle: 768 blocks = 8 XCDs x 96
  const int p = blockIdx.x;
  const int l = (p & 7) * 96 + (p >> 3);
  const int qt = l & 7;
  const int hb = l >> 3;
  const int h = hb % Hh, b = hb / Hh;
  const size_t rb = (size_t)b * Nseq;
  const int hoff = h * 64;

  const int qrow = qt * 128 + wid * 32 + l31;
  bf16x8 Qf[4];
#pragma unroll
  for (int ks = 0; ks < 4; ++ks)
    Qf[ks] = *(const bf16x8*)&qkb[(rb + qrow) * 1536 + hoff + ks * 16 + hi * 8];

  const unsigned short* Kb = qkb + rb * 1536 + 768 + hoff;          // + row*1536
  const unsigned short* Vb = vtb + ((size_t)b * 768 + hoff) * 1024;  // + d*1024

  float l_run = 0.f;
  f32x16 o0 = {}, o1 = {};

  for (int kt = 0; kt < NT; ++kt) {
    const int k0 = kt * 64;
    // V fragments first (used last -> latency hidden under QK+softmax)
    bf16x8 vf0[4], vf1[4], kf0[4], kf1[4];
#pragma unroll
    for (int ks = 0; ks < 4; ++ks) {
      const int co = (2 * ks + hi) * 8;
      vf0[ks] = *(const bf16x8*)&Vb[(size_t)l31 * 1024 + k0 + co];
      vf1[ks] = *(const bf16x8*)&Vb[(size_t)(l31 + 32) * 1024 + k0 + co];
    }
#pragma unroll
    for (int ks = 0; ks < 4; ++ks) {
      const int co = (2 * ks + hi) * 8;
      kf0[ks] = *(const bf16x8*)&Kb[(size_t)(k0 + l31) * 1536 + co];
      kf1[ks] = *(const bf16x8*)&Kb[(size_t)(k0 + l31 + 32) * 1536 + co];
    }
    // S^T = K . Q^T  (2 key-blocks of 32); scores already in exp2 domain
    f32x16 s0 = {}, s1 = {};
#pragma unroll
    for (int ks = 0; ks < 4; ++ks) {
      s0 = __builtin_amdgcn_mfma_f32_32x32x16_bf16(kf0[ks], Qf[ks], s0, 0, 0, 0);
      s1 = __builtin_amdgcn_mfma_f32_32x32x16_bf16(kf1[ks], Qf[ks], s1, 0, 0, 0);
    }
    // P = exp2(S) directly (no max subtraction: Q pre-scaled, |s| << 126)
#pragma unroll
    for (int i = 0; i < 16; ++i) {
      s0[i] = fexp2(s0[i]);
      s1[i] = fexp2(s1[i]);
    }
    // lane-local row-sum (tree); partner halves combined once after loop
    float a[8];
#pragma unroll
    for (int i = 0; i < 8; ++i)
      a[i] = (s0[i] + s0[i + 8]) + (s1[i] + s1[i + 8]);
#pragma unroll
    for (int st = 4; st >= 1; st >>= 1)
#pragma unroll
      for (int i = 0; i < st; ++i) a[i] += a[i + st];
    l_run += a[0];
    // pack P into A-frag bf16 layout: 16 cvt_pk + 8 permlane32_swap
    bf16x8 Pf[4];
#pragma unroll
    for (int ks = 0; ks < 4; ++ks) {
      const f32x16 sv = (ks >> 1) ? s1 : s0;
      const int e0 = 8 * (ks & 1);
      uint32_t pe01 = cvtpk_bf16(sv[e0 + 0], sv[e0 + 1]);
      uint32_t pe23 = cvtpk_bf16(sv[e0 + 2], sv[e0 + 3]);
      uint32_t po01 = cvtpk_bf16(sv[e0 + 4], sv[e0 + 5]);
      uint32_t po23 = cvtpk_bf16(sv[e0 + 6], sv[e0 + 7]);
      asm("v_permlane32_swap_b32 %0, %1" : "+v"(pe01), "+v"(po01));
      asm("v_permlane32_swap_b32 %0, %1" : "+v"(pe23), "+v"(po23));
      union {
        uint32_t w[4];
        bf16x8 v;
      } u;
      u.w[0] = pe01;
      u.w[1] = pe23;
      u.w[2] = po01;
      u.w[3] = po23;
      Pf[ks] = u.v;
    }
    // O^T += V^T . P^T  (2 d-blocks of 32)
#pragma unroll
    for (int ks = 0; ks < 4; ++ks) {
      o0 = __builtin_amdgcn_mfma_f32_32x32x16_bf16(vf0[ks], Pf[ks], o0, 0, 0, 0);
      o1 = __builtin_amdgcn_mfma_f32_32x32x16_bf16(vf1[ks], Pf[ks], o1, 0, 0, 0);
    }
  }
  // combine the two lane-halves' partial sums once
  const float lsum = l_run + __shfl_xor(l_run, 32);
  const float linv = 1.f / lsum;
  // epilogue: lane owns q-row; d = (reg&3) + 8*(reg>>2) + 4*hi (+32 for o1)
  const size_t obase = (size_t)(rb + qrow) * Dm + hoff;
#pragma unroll
  for (int g = 0; g < 4; ++g) {
    us4 a4 = {f2bf(o0[g * 4 + 0] * linv), f2bf(o0[g * 4 + 1] * linv),
              f2bf(o0[g * 4 + 2] * linv), f2bf(o0[g * 4 + 3] * linv)};
    *(us4*)&outb[obase + g * 8 + hi * 4] = a4;
    us4 b4 = {f2bf(o1[g * 4 + 0] * linv), f2bf(o1[g * 4 + 1] * linv),
              f2bf(o1[g * 4 + 2] * linv), f2bf(o1[g * 4 + 3] * linv)};
    *(us4*)&outb[obase + 32 + g * 8 + hi * 4] = b4;
  }
}

}  // namespace

extern "C" void kernel_launch(void* const* d_in, const int* in_sizes, int n_in,
                              void* d_out, int out_size, void* d_ws,
                              size_t ws_size, hipStream_t stream) {
  (void)in_sizes;
  (void)n_in;
  (void)out_size;
  (void)ws_size;
  const float* x = (const float*)d_in[0];      // [8192][768]
  const float* Wqkv = (const float*)d_in[1];   // [768][2304]
  const float* Wproj = (const float*)d_in[2];  // [768][768]
  const float* bproj = (const float*)d_in[3];  // [768]
  float* out = (float*)d_out;                  // [8192][768]

  char* w = (char*)d_ws;
  unsigned short* xb = (unsigned short*)w;      // 12.58 MB
  w += (size_t)Mrows * Dm * 2;
  unsigned short* wqkvt = (unsigned short*)w;   // 3.54 MB
  w += (size_t)threeD * Dm * 2;
  unsigned short* wprojt = (unsigned short*)w;  // 1.18 MB
  w += (size_t)Dm * Dm * 2;
  unsigned short* qkb = (unsigned short*)w;     // [8192][1536] 25.17 MB
  w += (size_t)Mrows * 1536 * 2;
  unsigned short* vtb = (unsigned short*)w;     // [96*64][1024] 12.58 MB
  w += (size_t)96 * 64 * 1024 * 2;
  unsigned short* attnb = (unsigned short*)w;   // 12.58 MB

  cast_f32_bf16<<<(Mrows * Dm / 4 + 255) / 256, 256, 0, stream>>>(
      x, xb, Mrows * Dm / 4);
  transpose_cast<<<dim3(threeD / 32, Dm / 32), 256, 0, stream>>>(
      Wqkv, wqkvt, Dm, threeD);
  transpose_cast<<<dim3(Dm / 32, Dm / 32), 256, 0, stream>>>(Wproj, wprojt, Dm, Dm);
  // qkv = x @ Wqkv; Q (pre-scaled) / K -> qkb, V -> vtb (transposed)
  gemm8<0, 9><<<dim3(576), 512, 0, stream>>>(xb, wqkvt, qkb, vtb, nullptr, Dm);
  // flash attention (128 q-rows per block, XCD-chunked 1D grid, no LDS)
  attn_mfma<<<dim3(768), 256, 0, stream>>>(qkb, vtb, attnb);
  // out = attn @ Wproj + bias (f32 out)
  gemm8<1, 3><<<dim3(192), 512, 0, stream>>>(attnb, wprojt, out, nullptr, bproj,
                                             Dm);
}

// Round 11
// 120.140 us; speedup vs baseline: 1.4523x; 1.4523x over previous
//
#include <hip/hip_runtime.h>
#include <math.h>
#include <stdint.h>

namespace {

constexpr int Nseq = 1024;
constexpr int Dm = 768;
constexpr int threeD = 2304;
constexpr int Mrows = 8192;
constexpr int Hh = 12;
// scale (1/8) * log2(e)
constexpr float kScaleLog2 = 0.18033688011112042f;

using bf16x8 = __attribute__((ext_vector_type(8))) short;
using f32x4 = __attribute__((ext_vector_type(4))) float;
using f32x16 = __attribute__((ext_vector_type(16))) float;
using us4 = __attribute__((ext_vector_type(4))) unsigned short;

__device__ __forceinline__ unsigned short f2bf(float f) {
  union { float f; uint32_t u; } v;
  v.f = f;
  uint32_t r = v.u + 0x7fffu + ((v.u >> 16) & 1u);
  return (unsigned short)(r >> 16);
}

__device__ __forceinline__ float fexp2(float x) {
#if __has_builtin(__builtin_amdgcn_exp2f)
  return __builtin_amdgcn_exp2f(x);
#else
  float r;
  asm("v_exp_f32 %0, %1\n\ts_nop 0" : "=v"(r) : "v"(x));
  return r;
#endif
}

__device__ __forceinline__ uint32_t cvtpk_bf16(float lo, float hi) {
  uint32_t r;
  asm("v_cvt_pk_bf16_f32 %0, %1, %2" : "=v"(r) : "v"(lo), "v"(hi));
  return r;
}

__device__ __forceinline__ void gload_lds16(const void* g, void* l) {
  __builtin_amdgcn_global_load_lds(
      (const __attribute__((address_space(1))) unsigned int*)(uintptr_t)g,
      (__attribute__((address_space(3))) unsigned int*)(uintptr_t)l, 16, 0, 0);
}

// ---------------------------------------------------------------------------
// fp32 -> bf16 elementwise cast (vectorized 4/thread)
// ---------------------------------------------------------------------------
__global__ __launch_bounds__(256) void cast_f32_bf16(
    const float* __restrict__ in, unsigned short* __restrict__ outp, int n4) {
  int i = blockIdx.x * blockDim.x + threadIdx.x;
  if (i < n4) {
    float4 v = ((const float4*)in)[i];
    us4 u = {f2bf(v.x), f2bf(v.y), f2bf(v.z), f2bf(v.w)};
    ((us4*)outp)[i] = u;
  }
}

// ---------------------------------------------------------------------------
// W[K][N] fp32 -> Wt[N][K] bf16 (32x32 LDS tile transpose)
// ---------------------------------------------------------------------------
__global__ __launch_bounds__(256) void transpose_cast(
    const float* __restrict__ W, unsigned short* __restrict__ Wt, int K, int N) {
  __shared__ unsigned short tile[32][33];
  const int n0 = blockIdx.x * 32, k0 = blockIdx.y * 32;
  const int tx = threadIdx.x & 31, ty = threadIdx.x >> 5;
#pragma unroll
  for (int i = 0; i < 32; i += 8)
    tile[ty + i][tx] = f2bf(W[(size_t)(k0 + ty + i) * N + n0 + tx]);
  __syncthreads();
#pragma unroll
  for (int i = 0; i < 32; i += 8)
    Wt[(size_t)(n0 + ty + i) * K + k0 + tx] = tile[tx][ty + i];
}

// ---------------------------------------------------------------------------
// bf16 MFMA GEMM (round-8 best-known): C = A[M][K] @ Bt[N][K]^T. BM x 128
// tile, BK=32, 4 waves, 3 LDS buffers, depth-2 prefetch with counted vmcnt,
// both-sides chunk swizzle (conflict-free). 1D grid, bijective XCD chunking.
// MODE 0 (QKV, BM=128, NCOLS=18): Q (pre-scaled) / K -> qkb; V -> vtb^T.
// MODE 1 (proj, BM=64, NCOLS=6): f32 out + bias. 768 blocks = 3/CU.
// ---------------------------------------------------------------------------
template <int MODE, int BM, int NCOLS>
__global__ __launch_bounds__(256) void gemm_bf16(
    const unsigned short* __restrict__ A, const unsigned short* __restrict__ Bt,
    void* __restrict__ C0, void* __restrict__ C1,
    const float* __restrict__ bias, int K) {
  constexpr int ASL = BM * 4;        // A 16B-slots per buffer (4 per row)
  constexpr int TS = ASL + 512;      // + B slots (128 rows x 4)
  constexpr int LPS = TS / 256;      // gload_lds issues per thread per stage
  constexpr int MF = BM / 32;        // m-fragments per wave
  __shared__ unsigned short As[3][ASL * 8];
  __shared__ unsigned short Bs[3][512 * 8];
  const int tid = threadIdx.x;
  const int wid = tid >> 6;
  const int lane = tid & 63;
  const int l15 = lane & 15, lg = lane >> 4;
  const int p = blockIdx.x;
  const int cpx = gridDim.x >> 3;
  const int l = (p & 7) * cpx + (p >> 3);
  const int row0 = (l / NCOLS) * BM, col0 = (l % NCOLS) * 128;
  const int wr = (wid >> 1) * (BM / 2), wc = (wid & 1) * 64;

  auto stage = [&](int k0, int bufi) {
    unsigned short* as = As[bufi];
    unsigned short* bs = Bs[bufi];
#pragma unroll
    for (int it = 0; it < LPS; ++it) {
      const int s = it * 256 + tid;
      if (s < ASL) {
        const int r = s >> 2, c = s & 3;
        const int g = c ^ ((r >> 1) & 3);  // inverse-swizzled source chunk
        gload_lds16(&A[(size_t)(row0 + r) * K + k0 + g * 8],
                    &as[(s & ~63) * 8]);
      } else {
        const int s2 = s - ASL;
        const int r = s2 >> 2, c = s2 & 3;
        const int g = c ^ ((r >> 1) & 3);
        gload_lds16(&Bt[(size_t)(col0 + r) * K + k0 + g * 8],
                    &bs[(s2 & ~63) * 8]);
      }
    }
  };

  f32x4 acc[MF][4] = {};
  const int nt = K / 32;  // 24
  stage(0, 0);
  stage(32, 1);
  for (int t = 0; t < nt; ++t) {
    const int cur = t % 3;
    if (t + 2 < nt) {
      stage((t + 2) * 32, (t + 2) % 3);
      asm volatile("s_waitcnt vmcnt(%0)" ::"i"(2 * LPS) : "memory");
    } else if (t + 1 < nt) {
      asm volatile("s_waitcnt vmcnt(%0)" ::"i"(LPS) : "memory");
    } else {
      asm volatile("s_waitcnt vmcnt(0)" ::: "memory");
    }
    __builtin_amdgcn_s_barrier();  // all waves' stage(t) landed
    bf16x8 av[MF], bv[4];
#pragma unroll
    for (int m = 0; m < MF; ++m) {
      const int ar = wr + m * 16 + l15;
      av[m] = *(const bf16x8*)&As[cur][(ar * 4 + (lg ^ ((ar >> 1) & 3))) * 8];
    }
#pragma unroll
    for (int n = 0; n < 4; ++n) {
      const int br = wc + n * 16 + l15;
      bv[n] = *(const bf16x8*)&Bs[cur][(br * 4 + (lg ^ ((br >> 1) & 3))) * 8];
    }
#pragma unroll
    for (int m = 0; m < MF; ++m)
#pragma unroll
      for (int n = 0; n < 4; ++n)
        acc[m][n] =
            __builtin_amdgcn_mfma_f32_16x16x32_bf16(av[m], bv[n], acc[m][n], 0, 0, 0);
    asm volatile("s_waitcnt lgkmcnt(0)" ::: "memory");
    __builtin_amdgcn_sched_barrier(0);
    __builtin_amdgcn_s_barrier();  // all reads of buf cur done -> reusable
  }
  if constexpr (MODE == 1) {
#pragma unroll
    for (int m = 0; m < MF; ++m)
#pragma unroll
      for (int n = 0; n < 4; ++n) {
        const int col = col0 + wc + n * 16 + l15;
#pragma unroll
        for (int rr = 0; rr < 4; ++rr)
          ((float*)C0)[(size_t)(row0 + wr + m * 16 + lg * 4 + rr) * Dm + col] =
              acc[m][n][rr] + bias[col];
      }
  } else if (col0 < 1536) {  // Q/K -> qk buffer, stride 1536; Q pre-scaled
#pragma unroll
    for (int m = 0; m < MF; ++m)
#pragma unroll
      for (int n = 0; n < 4; ++n) {
        const int col = col0 + wc + n * 16 + l15;
        const float qs = (col < 768) ? kScaleLog2 : 1.f;
#pragma unroll
        for (int rr = 0; rr < 4; ++rr)
          ((unsigned short*)C0)[(size_t)(row0 + wr + m * 16 + lg * 4 + rr) * 1536 +
                                col] = f2bf(acc[m][n][rr] * qs);
      }
  } else {  // V -> vtb[(b*12+h)*64+d][1024], 4 consecutive tokens per store
#pragma unroll
    for (int m = 0; m < MF; ++m)
#pragma unroll
      for (int n = 0; n < 4; ++n) {
        const int c = col0 + wc + n * 16 + l15 - 1536;  // h*64+d
        const int row = row0 + wr + m * 16 + lg * 4;    // first of 4 tokens
        const int bb = row >> 10, n0 = row & 1023;
        us4 pk = {f2bf(acc[m][n][0]), f2bf(acc[m][n][1]), f2bf(acc[m][n][2]),
                  f2bf(acc[m][n][3])};
        *(us4*)&((unsigned short*)C1)[((size_t)bb * 768 + c) * 1024 + n0] = pk;
      }
  }
}

// ---------------------------------------------------------------------------
// MFMA flash attention, swapped-operand, no-max exp2 softmax, with a 2-deep
// SOFTWARE PIPELINE inside each wave: QK^T(t+1) MFMAs are issued alongside
// softmax/pack/PV(t) (independent registers) so the wave's VALU work fills
// the MFMA shadow and vice versa. K/V triple-buffered in LDS (48 KB,
// 3 blocks/CU); stage(t+2) in flight with counted vmcnt(4).
// Block = 128 q-rows, 4 waves x 32 rows; XCD-chunked grid (768 = 8 x 96).
// Score regs ping-pong between two named f32x16 pairs (loop unrolled x2).
// ---------------------------------------------------------------------------
__global__ __launch_bounds__(256) void attn_mfma(
    const unsigned short* __restrict__ qkb, const unsigned short* __restrict__ vtb,
    unsigned short* __restrict__ outb) {
  constexpr int NT = Nseq / 64;  // 16
  __shared__ unsigned short Ks[3][64 * 64];
  __shared__ unsigned short Vs[3][64 * 64];
  const int tid = threadIdx.x;
  const int wid = tid >> 6, lane = tid & 63;
  const int l31 = lane & 31, hi = lane >> 5;
  // XCD-chunked swizzle: 768 blocks = 8 XCDs x 96
  const int p = blockIdx.x;
  const int l = (p & 7) * 96 + (p >> 3);
  const int qt = l & 7;
  const int hb = l >> 3;
  const int h = hb % Hh, b = hb / Hh;
  const size_t rb = (size_t)b * Nseq;
  const int hoff = h * 64;
  const size_t vbase = ((size_t)b * 768 + hoff) * 1024;

  const int qrow = qt * 128 + wid * 32 + l31;
  bf16x8 Qf[4];
#pragma unroll
  for (int ks = 0; ks < 4; ++ks)
    Qf[ks] = *(const bf16x8*)&qkb[(rb + qrow) * 1536 + hoff + ks * 16 + hi * 8];

  int strow[2], scol[2];
#pragma unroll
  for (int it = 0; it < 2; ++it) {
    const int ci = it * 256 + wid * 64 + lane;
    const int tr = ci >> 3, cc = ci & 7;
    strow[it] = tr;
    scol[it] = (cc ^ (tr & 7)) * 8;  // pre-swizzled source chunk (shorts)
  }

  auto stage = [&](int kt, int bufi) {
#pragma unroll
    for (int it = 0; it < 2; ++it) {
      const int ldsoff = (it * 256 + wid * 64) * 8;
      gload_lds16(&qkb[(rb + kt * 64 + strow[it]) * 1536 + 768 + hoff + scol[it]],
                  &Ks[bufi][ldsoff]);
      gload_lds16(&vtb[vbase + (size_t)strow[it] * 1024 + kt * 64 + scol[it]],
                  &Vs[bufi][ldsoff]);
    }
  };

  float l_run = 0.f;
  f32x16 o0 = {}, o1 = {};

  // QK^T of tile (from LDS buffer bidx) into d0/d1
  auto qk = [&](int bidx, f32x16& d0, f32x16& d1) {
    const unsigned short* ksb = Ks[bidx];
    d0 = {};
    d1 = {};
    __builtin_amdgcn_s_setprio(1);
#pragma unroll
    for (int ks = 0; ks < 4; ++ks) {
      const int c = 2 * ks + hi;
      {
        const int tr = l31;
        bf16x8 kf = *(const bf16x8*)&ksb[tr * 64 + ((c ^ (tr & 7)) * 8)];
        d0 = __builtin_amdgcn_mfma_f32_32x32x16_bf16(kf, Qf[ks], d0, 0, 0, 0);
      }
      {
        const int tr = l31 + 32;
        bf16x8 kf = *(const bf16x8*)&ksb[tr * 64 + ((c ^ (tr & 7)) * 8)];
        d1 = __builtin_amdgcn_mfma_f32_32x32x16_bf16(kf, Qf[ks], d1, 0, 0, 0);
      }
    }
    __builtin_amdgcn_s_setprio(0);
  };

  // softmax (exp2, lane-local sum) + pack to A-frag, then PV from Vs[bidx]
  auto finish = [&](int bidx, f32x16& s0, f32x16& s1) {
#pragma unroll
    for (int i = 0; i < 16; ++i) {
      s0[i] = fexp2(s0[i]);
      s1[i] = fexp2(s1[i]);
    }
    float a[8];
#pragma unroll
    for (int i = 0; i < 8; ++i)
      a[i] = (s0[i] + s0[i + 8]) + (s1[i] + s1[i + 8]);
#pragma unroll
    for (int st = 4; st >= 1; st >>= 1)
#pragma unroll
      for (int i = 0; i < st; ++i) a[i] += a[i + st];
    l_run += a[0];
    bf16x8 Pf[4];
#pragma unroll
    for (int ks = 0; ks < 4; ++ks) {
      const f32x16 sv = (ks >> 1) ? s1 : s0;
      const int e0 = 8 * (ks & 1);
      uint32_t pe01 = cvtpk_bf16(sv[e0 + 0], sv[e0 + 1]);
      uint32_t pe23 = cvtpk_bf16(sv[e0 + 2], sv[e0 + 3]);
      uint32_t po01 = cvtpk_bf16(sv[e0 + 4], sv[e0 + 5]);
      uint32_t po23 = cvtpk_bf16(sv[e0 + 6], sv[e0 + 7]);
      asm("v_permlane32_swap_b32 %0, %1" : "+v"(pe01), "+v"(po01));
      asm("v_permlane32_swap_b32 %0, %1" : "+v"(pe23), "+v"(po23));
      union {
        uint32_t w[4];
        bf16x8 v;
      } u;
      u.w[0] = pe01;
      u.w[1] = pe23;
      u.w[2] = po01;
      u.w[3] = po23;
      Pf[ks] = u.v;
    }
    const unsigned short* vsb = Vs[bidx];
    __builtin_amdgcn_s_setprio(1);
#pragma unroll
    for (int ks = 0; ks < 4; ++ks) {
      const int c = 2 * ks + hi;
      {
        const int tr = l31;
        bf16x8 vf = *(const bf16x8*)&vsb[tr * 64 + ((c ^ (tr & 7)) * 8)];
        o0 = __builtin_amdgcn_mfma_f32_32x32x16_bf16(vf, Pf[ks], o0, 0, 0, 0);
      }
      {
        const int tr = l31 + 32;
        bf16x8 vf = *(const bf16x8*)&vsb[tr * 64 + ((c ^ (tr & 7)) * 8)];
        o1 = __builtin_amdgcn_mfma_f32_32x32x16_bf16(vf, Pf[ks], o1, 0, 0, 0);
      }
    }
    __builtin_amdgcn_s_setprio(0);
  };

  // one pipeline step: cur holds scores(t); compute QK(t+1) into nxt while
  // finishing tile t.
  auto step = [&](int t, f32x16& c0, f32x16& c1, f32x16& n0, f32x16& n1) {
    if (t + 2 < NT) {
      stage(t + 2, (t + 2) % 3);
      asm volatile("s_waitcnt vmcnt(4)" ::: "memory");  // stage(t+1) landed
    } else {
      asm volatile("s_waitcnt vmcnt(0)" ::: "memory");
    }
    __builtin_amdgcn_s_barrier();
    if (t + 1 < NT) qk((t + 1) % 3, n0, n1);  // overlaps with finish(t)
    finish(t % 3, c0, c1);
    asm volatile("s_waitcnt lgkmcnt(0)" ::: "memory");
    __builtin_amdgcn_sched_barrier(0);
    __builtin_amdgcn_s_barrier();  // buffers (t)%3 fully consumed
  };

  // prologue: stage tiles 0,1; QK(0)
  stage(0, 0);
  stage(1, 1);
  asm volatile("s_waitcnt vmcnt(4)" ::: "memory");  // stage(0) landed
  __builtin_amdgcn_s_barrier();
  f32x16 sA0, sA1, sB0, sB1;
  qk(0, sA0, sA1);
  // main loop, unrolled x2 for the register ping-pong (NT = 16 even)
  for (int t = 0; t < NT; t += 2) {
    step(t, sA0, sA1, sB0, sB1);
    step(t + 1, sB0, sB1, sA0, sA1);
  }
  // combine the two lane-halves' partial sums once
  const float lsum = l_run + __shfl_xor(l_run, 32);
  const float linv = 1.f / lsum;
  // epilogue: lane owns q-row; d = (reg&3) + 8*(reg>>2) + 4*hi (+32 for o1)
  const size_t obase = (size_t)(rb + qrow) * Dm + hoff;
#pragma unroll
  for (int g = 0; g < 4; ++g) {
    us4 a4 = {f2bf(o0[g * 4 + 0] * linv), f2bf(o0[g * 4 + 1] * linv),
              f2bf(o0[g * 4 + 2] * linv), f2bf(o0[g * 4 + 3] * linv)};
    *(us4*)&outb[obase + g * 8 + hi * 4] = a4;
    us4 b4 = {f2bf(o1[g * 4 + 0] * linv), f2bf(o1[g * 4 + 1] * linv),
              f2bf(o1[g * 4 + 2] * linv), f2bf(o1[g * 4 + 3] * linv)};
    *(us4*)&outb[obase + 32 + g * 8 + hi * 4] = b4;
  }
}

}  // namespace

extern "C" void kernel_launch(void* const* d_in, const int* in_sizes, int n_in,
                              void* d_out, int out_size, void* d_ws,
                              size_t ws_size, hipStream_t stream) {
  (void)in_sizes;
  (void)n_in;
  (void)out_size;
  (void)ws_size;
  const float* x = (const float*)d_in[0];      // [8192][768]
  const float* Wqkv = (const float*)d_in[1];   // [768][2304]
  const float* Wproj = (const float*)d_in[2];  // [768][768]
  const float* bproj = (const float*)d_in[3];  // [768]
  float* out = (float*)d_out;                  // [8192][768]

  char* w = (char*)d_ws;
  unsigned short* xb = (unsigned short*)w;      // 12.58 MB
  w += (size_t)Mrows * Dm * 2;
  unsigned short* wqkvt = (unsigned short*)w;   // 3.54 MB
  w += (size_t)threeD * Dm * 2;
  unsigned short* wprojt = (unsigned short*)w;  // 1.18 MB
  w += (size_t)Dm * Dm * 2;
  unsigned short* qkb = (unsigned short*)w;     // [8192][1536] 25.17 MB
  w += (size_t)Mrows * 1536 * 2;
  unsigned short* vtb = (unsigned short*)w;     // [96*64][1024] 12.58 MB
  w += (size_t)96 * 64 * 1024 * 2;
  unsigned short* attnb = (unsigned short*)w;   // 12.58 MB

  cast_f32_bf16<<<(Mrows * Dm / 4 + 255) / 256, 256, 0, stream>>>(
      x, xb, Mrows * Dm / 4);
  transpose_cast<<<dim3(threeD / 32, Dm / 32), 256, 0, stream>>>(
      Wqkv, wqkvt, Dm, threeD);
  transpose_cast<<<dim3(Dm / 32, Dm / 32), 256, 0, stream>>>(Wproj, wprojt, Dm, Dm);
  // qkv = x @ Wqkv; Q (pre-scaled) / K -> qkb, V -> vtb (transposed)
  gemm_bf16<0, 128, 18><<<dim3(1152), 256, 0, stream>>>(
      xb, wqkvt, qkb, vtb, nullptr, Dm);
  // flash attention (128 q-rows per block, XCD-chunked, 2-deep pipeline)
  attn_mfma<<<dim3(768), 256, 0, stream>>>(qkb, vtb, attnb);
  // out = attn @ Wproj + bias (f32 out), 64x128 tiles -> 768 blocks = 3/CU
  gemm_bf16<1, 64, 6><<<dim3(768), 256, 0, stream>>>(
      attnb, wprojt, out, nullptr, bproj, Dm);
}